// Round 6
// baseline (170.392 us; speedup 1.0000x reference)
//
#include <hip/hip_runtime.h>
#include <math.h>

// FeedForwardQuantum, analytically collapsed circuit:
//   z_j = cos(theta_j) * cos(x.W1_j + b1_j)
//   ex[w] = prod_{j<=w} z_j (w>=1); ex[0] = prod_{j=1..7} z_j
//   out = relu(ex @ W2^T + b2)
//
// Structure: persistent 4-wave blocks, W2 staged to LDS once; each wave
// pipelines NITER=2 iterations of TPT=2 tokens so iter i+1's x loads are in
// flight while iter i's GEMM2 computes and stores drain -> mixed HBM stream.

constexpr int EMBED = 768;
constexpr int NQ    = 8;
constexpr int BLOCK = 256;            // 4 waves
constexpr int WAVES = 4;
constexpr int TPT   = 2;              // tokens per pipeline stage
constexpr int NITER = 2;              // pipeline stages per wave
constexpr int TPW   = TPT * NITER;    // 4 tokens per wave
constexpr int TPB   = WAVES * TPW;    // 16 tokens per block

typedef float vfloat4 __attribute__((ext_vector_type(4)));

__global__ __launch_bounds__(BLOCK, 4) void ffq_kernel(
    const float* __restrict__ x,  const float* __restrict__ W1,
    const float* __restrict__ b1, const float* __restrict__ theta,
    const float* __restrict__ W2, const float* __restrict__ b2,
    float* __restrict__ out, int ntok)
{
    __shared__ float w2t[NQ][EMBED];             // transposed W2 (24 KB)
    __shared__ float zbuf[2][WAVES][TPT][NQ];    // double-buffered per-wave z

    const int tid  = threadIdx.x;
    const int wave = tid >> 6;
    const int lane = tid & 63;

    const int tbase = (blockIdx.x * WAVES + wave) * TPW;   // wave's first token
    const float4* x4 = (const float4*)x;

    // ---- issue iter-0 x loads first: HBM traffic starts immediately ----
    float4 xv[TPT][3];
    #pragma unroll
    for (int it = 0; it < TPT; ++it) {
        const int t = min(tbase + it, ntok - 1);
        #pragma unroll
        for (int k = 0; k < 3; ++k)
            xv[it][k] = x4[(size_t)t * (EMBED / 4) + lane + 64 * k];
    }

    // ---- stage W2 transposed (once): coalesced reads, scalar scatter writes ----
    {
        const float4* W24 = (const float4*)W2;
        for (int i = tid; i < EMBED * NQ / 4; i += BLOCK) {
            const float4 v = W24[i];
            const int f = 4 * i;                 // flat = e*8 + q
            w2t[(f + 0) & 7][(f + 0) >> 3] = v.x;
            w2t[(f + 1) & 7][(f + 1) >> 3] = v.y;
            w2t[(f + 2) & 7][(f + 2) >> 3] = v.z;
            w2t[(f + 3) & 7][(f + 3) >> 3] = v.w;
        }
    }

    const int q_own = lane & 7;
    const float costh = __cosf(theta[q_own]);
    const float b1q   = b1[q_own];

    // hoist b2 (reused every iteration)
    const float4* b24 = (const float4*)b2;
    float4 bb[3];
    #pragma unroll
    for (int k = 0; k < 3; ++k) bb[k] = b24[lane + 64 * k];

    __syncthreads();   // w2t ready; the only block-wide barrier

    const float4* W14 = (const float4*)W1;
    const bool c0 = lane & 1, c1 = lane & 2, c2 = lane & 4;
    const int osel = (lane >> 3) & (TPT - 1);

    #pragma unroll
    for (int i = 0; i < NITER; ++i) {
        // ---- GEMM1 partials: W1 from L1/L2, shared across TPT tokens ----
        float acc[TPT][NQ];
        #pragma unroll
        for (int it = 0; it < TPT; ++it)
            #pragma unroll
            for (int q = 0; q < NQ; ++q) acc[it][q] = 0.f;

        #pragma unroll
        for (int k = 0; k < 3; ++k) {
            const int idx = lane + 64 * k;
            #pragma unroll
            for (int q = 0; q < NQ; ++q) {
                const float4 w = W14[q * (EMBED / 4) + idx];
                #pragma unroll
                for (int it = 0; it < TPT; ++it) {
                    acc[it][q] = fmaf(xv[it][k].x, w.x, fmaf(xv[it][k].y, w.y,
                                 fmaf(xv[it][k].z, w.z, fmaf(xv[it][k].w, w.w, acc[it][q]))));
                }
            }
        }

        // ---- prefetch next iteration's x while this iter finishes ----
        float4 xn[TPT][3];
        if (i + 1 < NITER) {
            #pragma unroll
            for (int it = 0; it < TPT; ++it) {
                const int t = min(tbase + (i + 1) * TPT + it, ntok - 1);
                #pragma unroll
                for (int k = 0; k < 3; ++k)
                    xn[it][k] = x4[(size_t)t * (EMBED / 4) + lane + 64 * k];
            }
        }

        // ---- packed reduce: 10 shuffles/token -> lane holds sum for q=lane&7 ----
        float S[TPT];
        #pragma unroll
        for (int it = 0; it < TPT; ++it) {
            float k0 = c0 ? acc[it][1] : acc[it][0], g0 = c0 ? acc[it][0] : acc[it][1];
            float k1 = c0 ? acc[it][3] : acc[it][2], g1 = c0 ? acc[it][2] : acc[it][3];
            float k2 = c0 ? acc[it][5] : acc[it][4], g2 = c0 ? acc[it][4] : acc[it][5];
            float k3 = c0 ? acc[it][7] : acc[it][6], g3 = c0 ? acc[it][6] : acc[it][7];
            float v0 = k0 + __shfl_xor(g0, 1, 64);
            float v1 = k1 + __shfl_xor(g1, 1, 64);
            float v2 = k2 + __shfl_xor(g2, 1, 64);
            float v3 = k3 + __shfl_xor(g3, 1, 64);
            float ka = c1 ? v1 : v0, ga = c1 ? v0 : v1;
            float kb = c1 ? v3 : v2, gb = c1 ? v2 : v3;
            float u0 = ka + __shfl_xor(ga, 2, 64);
            float u1 = kb + __shfl_xor(gb, 2, 64);
            float kc = c2 ? u1 : u0, gc = c2 ? u0 : u1;
            float s  = kc + __shfl_xor(gc, 4, 64);
            s += __shfl_xor(s, 8, 64);
            s += __shfl_xor(s, 16, 64);
            s += __shfl_xor(s, 32, 64);
            S[it] = s;
        }

        // ---- one cosf/lane; octet parity picks the token it publishes ----
        const float Ssel = osel ? S[TPT - 1] : S[0];
        const float zval = costh * __cosf(Ssel + b1q);
        zbuf[i & 1][wave][osel][q_own] = zval;

        // ---- read back sorted z[8] (wave-local broadcast), prefix products ----
        float ex[TPT][NQ];
        #pragma unroll
        for (int it = 0; it < TPT; ++it) {
            const float4 za = ((const float4*)zbuf[i & 1][wave][it])[0];
            const float4 zb = ((const float4*)zbuf[i & 1][wave][it])[1];
            const float zq[NQ] = { za.x, za.y, za.z, za.w, zb.x, zb.y, zb.z, zb.w };
            float p = zq[0];
            #pragma unroll
            for (int q = 1; q < NQ; ++q) { p *= zq[q]; ex[it][q] = p; }
            float sfx = zq[1];
            #pragma unroll
            for (int q = 2; q < NQ; ++q) sfx *= zq[q];
            ex[it][0] = sfx;
        }

        // ---- GEMM2 + bias + relu: conflict-free b128 LDS reads, NT stores ----
        #pragma unroll
        for (int k = 0; k < 3; ++k) {
            const int idx = lane + 64 * k;
            float4 r[TPT];
            #pragma unroll
            for (int it = 0; it < TPT; ++it) r[it] = bb[k];
            #pragma unroll
            for (int q = 0; q < NQ; ++q) {
                const float4 w = ((const float4*)&w2t[q][0])[idx];
                #pragma unroll
                for (int it = 0; it < TPT; ++it) {
                    r[it].x = fmaf(ex[it][q], w.x, r[it].x);
                    r[it].y = fmaf(ex[it][q], w.y, r[it].y);
                    r[it].z = fmaf(ex[it][q], w.z, r[it].z);
                    r[it].w = fmaf(ex[it][q], w.w, r[it].w);
                }
            }
            #pragma unroll
            for (int it = 0; it < TPT; ++it) {
                const int t = min(tbase + i * TPT + it, ntok - 1);
                vfloat4 o = { fmaxf(r[it].x, 0.f), fmaxf(r[it].y, 0.f),
                              fmaxf(r[it].z, 0.f), fmaxf(r[it].w, 0.f) };
                __builtin_nontemporal_store(o, (vfloat4*)(out + (size_t)t * EMBED) + idx);
            }
        }

        // rotate pipeline registers
        if (i + 1 < NITER) {
            #pragma unroll
            for (int it = 0; it < TPT; ++it)
                #pragma unroll
                for (int k = 0; k < 3; ++k) xv[it][k] = xn[it][k];
        }
    }
}

extern "C" void kernel_launch(void* const* d_in, const int* in_sizes, int n_in,
                              void* d_out, int out_size, void* d_ws, size_t ws_size,
                              hipStream_t stream) {
    const float* x     = (const float*)d_in[0];
    const float* W1    = (const float*)d_in[1];
    const float* b1    = (const float*)d_in[2];
    const float* theta = (const float*)d_in[3];
    const float* W2    = (const float*)d_in[4];
    const float* b2    = (const float*)d_in[5];
    float* out = (float*)d_out;

    const int ntok = in_sizes[0] / EMBED;          // 16384
    const int grid = (ntok + TPB - 1) / TPB;       // 1024 = 4 blocks/CU
    hipLaunchKernelGGL(ffq_kernel, dim3(grid), dim3(BLOCK), 0, stream,
                       x, W1, b1, theta, W2, b2, out, ntok);
}

// Round 7
// 29.211 us; speedup vs baseline: 5.8331x; 5.8331x over previous
//
#include <hip/hip_runtime.h>
#include <math.h>

// FeedForwardQuantum, analytically collapsed circuit:
//   z_j = cos(theta_j) * cos(x.W1_j + b1_j)
//   ex[w] = prod_{j<=w} z_j (w>=1); ex[0] = prod_{j=1..7} z_j
//   out = relu(ex @ W2^T + b2)
//
// Two phase-homogeneous kernels:
//   A: read-bound  — z[t][8] from x (50 MB read, 0.5 MB write to ws);
//      block 0 additionally transposes W2 -> W2T in ws.
//   B: write-bound — out from z + W2T (50 MB NT stores).
// No LDS, no __syncthreads in either kernel.

constexpr int EMBED = 768;
constexpr int NQ    = 8;
constexpr int BLOCK = 256;           // 4 waves
constexpr int WAVES = 4;
constexpr int TPT   = 2;             // tokens per wave
constexpr int TPB   = WAVES * TPT;   // 8 tokens/block

typedef float vfloat4 __attribute__((ext_vector_type(4)));

// ---------------- Kernel A: z + W2 transpose ----------------
__global__ __launch_bounds__(BLOCK, 8) void ffq_zkern(
    const float* __restrict__ x,  const float* __restrict__ W1,
    const float* __restrict__ b1, const float* __restrict__ theta,
    const float* __restrict__ W2,
    float* __restrict__ zws, float* __restrict__ w2t, int ntok)
{
    const int tid  = threadIdx.x;
    const int wave = tid >> 6;
    const int lane = tid & 63;
    const int t0   = (blockIdx.x * WAVES + wave) * TPT;
    const int ta   = min(t0, ntok - 1);
    const int tb   = min(t0 + 1, ntok - 1);

    // ---- x loads first (named regs, no arrays that could spill) ----
    const float4* x4 = (const float4*)x;
    const float4 xa0 = x4[(size_t)ta * (EMBED / 4) + lane];
    const float4 xa1 = x4[(size_t)ta * (EMBED / 4) + lane + 64];
    const float4 xa2 = x4[(size_t)ta * (EMBED / 4) + lane + 128];
    const float4 xb0 = x4[(size_t)tb * (EMBED / 4) + lane];
    const float4 xb1 = x4[(size_t)tb * (EMBED / 4) + lane + 64];
    const float4 xb2 = x4[(size_t)tb * (EMBED / 4) + lane + 128];

    // ---- GEMM1 partials: W1 from L1/L2, shared across both tokens ----
    const float4* W14 = (const float4*)W1;
    float acc0[NQ], acc1[NQ];
    #pragma unroll
    for (int q = 0; q < NQ; ++q) { acc0[q] = 0.f; acc1[q] = 0.f; }
    #pragma unroll
    for (int q = 0; q < NQ; ++q) {
        const float4 w0 = W14[q * (EMBED / 4) + lane];
        const float4 w1 = W14[q * (EMBED / 4) + lane + 64];
        const float4 w2 = W14[q * (EMBED / 4) + lane + 128];
        float s0 = 0.f, s1 = 0.f;
        s0 = fmaf(xa0.x, w0.x, fmaf(xa0.y, w0.y, fmaf(xa0.z, w0.z, fmaf(xa0.w, w0.w, s0))));
        s0 = fmaf(xa1.x, w1.x, fmaf(xa1.y, w1.y, fmaf(xa1.z, w1.z, fmaf(xa1.w, w1.w, s0))));
        s0 = fmaf(xa2.x, w2.x, fmaf(xa2.y, w2.y, fmaf(xa2.z, w2.z, fmaf(xa2.w, w2.w, s0))));
        s1 = fmaf(xb0.x, w0.x, fmaf(xb0.y, w0.y, fmaf(xb0.z, w0.z, fmaf(xb0.w, w0.w, s1))));
        s1 = fmaf(xb1.x, w1.x, fmaf(xb1.y, w1.y, fmaf(xb1.z, w1.z, fmaf(xb1.w, w1.w, s1))));
        s1 = fmaf(xb2.x, w2.x, fmaf(xb2.y, w2.y, fmaf(xb2.z, w2.z, fmaf(xb2.w, w2.w, s1))));
        acc0[q] = s0; acc1[q] = s1;
    }

    // ---- packed reduce: 10 shuffles/token -> lane holds sum for q = lane&7 ----
    const bool c0 = lane & 1, c1 = lane & 2, c2 = lane & 4;
    float S0, S1;
    {
        float k0 = c0 ? acc0[1] : acc0[0], g0 = c0 ? acc0[0] : acc0[1];
        float k1 = c0 ? acc0[3] : acc0[2], g1 = c0 ? acc0[2] : acc0[3];
        float k2 = c0 ? acc0[5] : acc0[4], g2 = c0 ? acc0[4] : acc0[5];
        float k3 = c0 ? acc0[7] : acc0[6], g3 = c0 ? acc0[6] : acc0[7];
        float v0 = k0 + __shfl_xor(g0, 1, 64);
        float v1 = k1 + __shfl_xor(g1, 1, 64);
        float v2 = k2 + __shfl_xor(g2, 1, 64);
        float v3 = k3 + __shfl_xor(g3, 1, 64);
        float ka = c1 ? v1 : v0, ga = c1 ? v0 : v1;
        float kb = c1 ? v3 : v2, gb = c1 ? v2 : v3;
        float u0 = ka + __shfl_xor(ga, 2, 64);
        float u1 = kb + __shfl_xor(gb, 2, 64);
        float kc = c2 ? u1 : u0, gc = c2 ? u0 : u1;
        float s  = kc + __shfl_xor(gc, 4, 64);
        s += __shfl_xor(s, 8, 64);
        s += __shfl_xor(s, 16, 64);
        s += __shfl_xor(s, 32, 64);
        S0 = s;
    }
    {
        float k0 = c0 ? acc1[1] : acc1[0], g0 = c0 ? acc1[0] : acc1[1];
        float k1 = c0 ? acc1[3] : acc1[2], g1 = c0 ? acc1[2] : acc1[3];
        float k2 = c0 ? acc1[5] : acc1[4], g2 = c0 ? acc1[4] : acc1[5];
        float k3 = c0 ? acc1[7] : acc1[6], g3 = c0 ? acc1[6] : acc1[7];
        float v0 = k0 + __shfl_xor(g0, 1, 64);
        float v1 = k1 + __shfl_xor(g1, 1, 64);
        float v2 = k2 + __shfl_xor(g2, 1, 64);
        float v3 = k3 + __shfl_xor(g3, 1, 64);
        float ka = c1 ? v1 : v0, ga = c1 ? v0 : v1;
        float kb = c1 ? v3 : v2, gb = c1 ? v2 : v3;
        float u0 = ka + __shfl_xor(ga, 2, 64);
        float u1 = kb + __shfl_xor(gb, 2, 64);
        float kc = c2 ? u1 : u0, gc = c2 ? u0 : u1;
        float s  = kc + __shfl_xor(gc, 4, 64);
        s += __shfl_xor(s, 8, 64);
        s += __shfl_xor(s, 16, 64);
        s += __shfl_xor(s, 32, 64);
        S1 = s;
    }

    // ---- z for (token = t0 + osel, q = lane&7); lanes 0-15 store 64B coalesced ----
    const int q_own = lane & 7;
    const int osel  = (lane >> 3) & 1;
    const float zval = __cosf(theta[q_own]) * __cosf((osel ? S1 : S0) + b1[q_own]);
    if (lane < 16) zws[(size_t)t0 * NQ + lane] = zval;

    // ---- block 0: transpose W2 -> W2T[q][e] (coalesced writes) ----
    if (blockIdx.x == 0) {
        for (int o = tid; o < NQ * EMBED; o += BLOCK)
            w2t[o] = W2[(o % EMBED) * NQ + (o / EMBED)];
    }
}

// ---------------- Kernel B: out = relu(ex @ W2^T + b2) ----------------
__global__ __launch_bounds__(BLOCK, 8) void ffq_okern(
    const float* __restrict__ zws, const float* __restrict__ w2t,
    const float* __restrict__ b2,  float* __restrict__ out, int ntok)
{
    const int tid  = threadIdx.x;
    const int wave = tid >> 6;
    const int lane = tid & 63;
    const int t0   = (blockIdx.x * WAVES + wave) * TPT;
    const int ta   = min(t0, ntok - 1);
    const int tb   = min(t0 + 1, ntok - 1);

    // z[8] per token: uniform-address broadcast loads
    const float4* z4 = (const float4*)(zws + (size_t)t0 * NQ);
    const float4 za0 = z4[0], za1 = z4[1];     // token ta
    const float4 zb0 = z4[2], zb1 = z4[3];     // token tb

    // prefix products -> ex
    float ex0[NQ], ex1[NQ];
    {
        const float zq[NQ] = { za0.x, za0.y, za0.z, za0.w, za1.x, za1.y, za1.z, za1.w };
        float p = zq[0];
        #pragma unroll
        for (int q = 1; q < NQ; ++q) { p *= zq[q]; ex0[q] = p; }
        float sfx = zq[1];
        #pragma unroll
        for (int q = 2; q < NQ; ++q) sfx *= zq[q];
        ex0[0] = sfx;
    }
    {
        const float zq[NQ] = { zb0.x, zb0.y, zb0.z, zb0.w, zb1.x, zb1.y, zb1.z, zb1.w };
        float p = zq[0];
        #pragma unroll
        for (int q = 1; q < NQ; ++q) { p *= zq[q]; ex1[q] = p; }
        float sfx = zq[1];
        #pragma unroll
        for (int q = 2; q < NQ; ++q) sfx *= zq[q];
        ex1[0] = sfx;
    }

    // GEMM2 + bias + relu: W2T coalesced float4 (L1-hot), NT stores
    const float4* W2T4 = (const float4*)w2t;
    const float4* b24  = (const float4*)b2;
    #pragma unroll
    for (int k = 0; k < 3; ++k) {
        const int idx = lane + 64 * k;
        const float4 bb = b24[idx];
        float4 r0 = bb, r1 = bb;
        #pragma unroll
        for (int q = 0; q < NQ; ++q) {
            const float4 w = W2T4[q * (EMBED / 4) + idx];
            r0.x = fmaf(ex0[q], w.x, r0.x);
            r0.y = fmaf(ex0[q], w.y, r0.y);
            r0.z = fmaf(ex0[q], w.z, r0.z);
            r0.w = fmaf(ex0[q], w.w, r0.w);
            r1.x = fmaf(ex1[q], w.x, r1.x);
            r1.y = fmaf(ex1[q], w.y, r1.y);
            r1.z = fmaf(ex1[q], w.z, r1.z);
            r1.w = fmaf(ex1[q], w.w, r1.w);
        }
        vfloat4 o0 = { fmaxf(r0.x, 0.f), fmaxf(r0.y, 0.f), fmaxf(r0.z, 0.f), fmaxf(r0.w, 0.f) };
        vfloat4 o1 = { fmaxf(r1.x, 0.f), fmaxf(r1.y, 0.f), fmaxf(r1.z, 0.f), fmaxf(r1.w, 0.f) };
        __builtin_nontemporal_store(o0, (vfloat4*)(out + (size_t)ta * EMBED) + idx);
        __builtin_nontemporal_store(o1, (vfloat4*)(out + (size_t)tb * EMBED) + idx);
    }
}

extern "C" void kernel_launch(void* const* d_in, const int* in_sizes, int n_in,
                              void* d_out, int out_size, void* d_ws, size_t ws_size,
                              hipStream_t stream) {
    const float* x     = (const float*)d_in[0];
    const float* W1    = (const float*)d_in[1];
    const float* b1    = (const float*)d_in[2];
    const float* theta = (const float*)d_in[3];
    const float* W2    = (const float*)d_in[4];
    const float* b2    = (const float*)d_in[5];
    float* out = (float*)d_out;

    const int ntok = in_sizes[0] / EMBED;            // 16384
    float* zws = (float*)d_ws;                       // ntok*8 floats = 512 KB
    float* w2t = zws + (size_t)ntok * NQ;            // 6144 floats = 24 KB

    const int grid = (ntok + TPB - 1) / TPB;         // 2048
    hipLaunchKernelGGL(ffq_zkern, dim3(grid), dim3(BLOCK), 0, stream,
                       x, W1, b1, theta, W2, zws, w2t, ntok);
    hipLaunchKernelGGL(ffq_okern, dim3(grid), dim3(BLOCK), 0, stream,
                       zws, w2t, b2, out, ntok);
}